// Round 2
// baseline (489.186 us; speedup 1.0000x reference)
//
#include <hip/hip_runtime.h>

// LocallyConnectedLayer: out[b,o,p] = bias[p,o] + sum_{c,di,dj} x[b,c,i+di,j+dj] * W[p,o,c*9+di*3+dj]
// B=32 C=96 H=W=32 OC=96 K=3 S=1 -> oh=ow=30, P=900, Kdim=864.
// One block per p: 32x96 output tile = A(32x864) @ W_p(96x864)^T.
// Weight (298.6 MB f32) is read exactly once, coalesced float4 -> memory-bound target ~51us.

namespace {
constexpr int BATCH = 32;
constexpr int CIN   = 96;
constexpr int HIN   = 32;
constexpr int WIN   = 32;
constexpr int OC    = 96;
constexpr int OH    = 30;
constexpr int OW    = 30;
constexpr int NP    = OH * OW;     // 900
constexpr int KTOT  = CIN * 9;     // 864
constexpr int KC    = 72;          // chunk: 8 channels x 9 taps
constexpr int NCH   = KTOT / KC;   // 12
constexpr int NTHR  = 192;         // 3 waves
constexpr int APAD  = 36;          // k-major row stride for A (mult of 4 -> aligned b128)
constexpr int WPAD  = 100;         // k-major row stride for W
}

__global__ __launch_bounds__(NTHR, 3)
void lc_forward(const float* __restrict__ x,
                const float* __restrict__ weight,
                const float* __restrict__ bias,
                float* __restrict__ out)
{
    __shared__ float Alds[KC][APAD];   // [k][b]  10.1 KB
    __shared__ float Wlds[KC][WPAD];   // [k][o]  28.1 KB  -> 4 blocks/CU

    const int p    = blockIdx.x;
    const int pi   = p / OW;
    const int pj   = p - pi * OW;
    const int t    = threadIdx.x;
    const int lane = t & 63;
    const int wv   = t >> 6;                    // 0..2

    // compute-phase mapping: conflict-free LDS reads.
    // b-group = lane/8 (8 groups x 4 batch), o-group = wave*8 + lane%8 (covers 96 o over 3 waves)
    const int b0 = (lane >> 3) << 2;            // 0,4,...,28
    const int o0 = wv * 32 + ((lane & 7) << 2); // 0..92

    float acc[4][4] = {};

    const float* wp    = weight + (size_t)p * (OC * KTOT);
    const float* xbase = x + pi * WIN + pj;

    for (int ch = 0; ch < NCH; ++ch) {
        // ---- stage patches A[k][b], k = cc*9 + (di*3+dj), channel = ch*8+cc ----
        #pragma unroll
        for (int it = 0; it < (BATCH * KC) / NTHR; ++it) {   // 12
            const int e  = t + it * NTHR;                    // 0..2303
            const int b  = e / KC;
            const int rm = e - b * KC;                       // cc*9 + r
            const int cc = rm / 9;
            const int r  = rm - cc * 9;
            const int di = r / 3;
            const int dj = r - di * 3;
            Alds[rm][b] = xbase[(size_t)b * (CIN * HIN * WIN)
                                + (ch * 8 + cc) * (HIN * WIN)
                                + di * WIN + dj];
        }
        // ---- stage weights W[k][o], coalesced float4 along k ----
        const float* wc = wp + ch * KC;
        #pragma unroll
        for (int it = 0; it < (OC * KC / 4) / NTHR; ++it) {  // 9
            const int f  = t + it * NTHR;                    // 0..1727
            const int o  = f / (KC / 4);                     // /18
            const int kq = f - o * (KC / 4);
            const float4 v = *reinterpret_cast<const float4*>(wc + (size_t)o * KTOT + (kq << 2));
            const int kk = kq << 2;
            Wlds[kk + 0][o] = v.x;
            Wlds[kk + 1][o] = v.y;
            Wlds[kk + 2][o] = v.z;
            Wlds[kk + 3][o] = v.w;
        }
        __syncthreads();

        // ---- compute: 16 FMA per k per thread, 2 conflict-free ds_read_b128 ----
        #pragma unroll 4
        for (int kk = 0; kk < KC; ++kk) {
            const float4 a = *reinterpret_cast<const float4*>(&Alds[kk][b0]);
            const float4 w = *reinterpret_cast<const float4*>(&Wlds[kk][o0]);
            acc[0][0] = fmaf(a.x, w.x, acc[0][0]);
            acc[0][1] = fmaf(a.x, w.y, acc[0][1]);
            acc[0][2] = fmaf(a.x, w.z, acc[0][2]);
            acc[0][3] = fmaf(a.x, w.w, acc[0][3]);
            acc[1][0] = fmaf(a.y, w.x, acc[1][0]);
            acc[1][1] = fmaf(a.y, w.y, acc[1][1]);
            acc[1][2] = fmaf(a.y, w.z, acc[1][2]);
            acc[1][3] = fmaf(a.y, w.w, acc[1][3]);
            acc[2][0] = fmaf(a.z, w.x, acc[2][0]);
            acc[2][1] = fmaf(a.z, w.y, acc[2][1]);
            acc[2][2] = fmaf(a.z, w.z, acc[2][2]);
            acc[2][3] = fmaf(a.z, w.w, acc[2][3]);
            acc[3][0] = fmaf(a.w, w.x, acc[3][0]);
            acc[3][1] = fmaf(a.w, w.y, acc[3][1]);
            acc[3][2] = fmaf(a.w, w.z, acc[3][2]);
            acc[3][3] = fmaf(a.w, w.w, acc[3][3]);
        }
        __syncthreads();
    }

    // ---- epilogue: bias + scatter store (out[b][o][p], p fixed) ----
    const float* bp = bias + (size_t)p * OC;
    #pragma unroll
    for (int i = 0; i < 4; ++i) {
        #pragma unroll
        for (int j = 0; j < 4; ++j) {
            out[((size_t)(b0 + i) * OC + (o0 + j)) * NP + p] = acc[i][j] + bp[o0 + j];
        }
    }
}

extern "C" void kernel_launch(void* const* d_in, const int* in_sizes, int n_in,
                              void* d_out, int out_size, void* d_ws, size_t ws_size,
                              hipStream_t stream) {
    const float* x  = (const float*)d_in[0];
    const float* w  = (const float*)d_in[1];
    const float* bi = (const float*)d_in[2];
    float* o        = (float*)d_out;
    lc_forward<<<dim3(NP), dim3(NTHR), 0, stream>>>(x, w, bi, o);
}